// Round 16
// baseline (193.601 us; speedup 1.0000x reference)
//
#include <hip/hip_runtime.h>
#include <stdint.h>

typedef short short8 __attribute__((ext_vector_type(8)));
typedef short short4v __attribute__((ext_vector_type(4)));
typedef float f32x4 __attribute__((ext_vector_type(4)));
typedef float f32x16 __attribute__((ext_vector_type(16)));
typedef unsigned int u32x4 __attribute__((ext_vector_type(4)));

#define LOG2E 1.44269504088896f
#define QSCALE (0.125f * LOG2E)

__device__ __forceinline__ unsigned short f2b(float f) {
  union { float f; unsigned int u; } x; x.f = f;
  unsigned int u = x.u;
  unsigned int r = (u + 0x7fffu + ((u >> 16) & 1u)) >> 16;
  return (unsigned short)r;
}
__device__ __forceinline__ float b2f(unsigned short s) {
  union { unsigned int u; float f; } x; x.u = ((unsigned int)s) << 16;
  return x.f;
}
__device__ __forceinline__ void gl16(const void* g, void* l) {
  __builtin_amdgcn_global_load_lds((const __attribute__((address_space(1))) void*)g,
                                   (__attribute__((address_space(3))) void*)l, 16, 0, 0);
}
__device__ __forceinline__ unsigned int cvtpk(float lo, float hi) {
  unsigned int r;
  asm("v_cvt_pk_bf16_f32 %0, %1, %2" : "=v"(r) : "v"(lo), "v"(hi));
  return r;
}
__device__ __forceinline__ void plswap(unsigned int& a, unsigned int& b) {
  asm volatile("v_permlane32_swap_b32 %0, %1" : "+v"(a), "+v"(b));
}

// ------- merged prologue: castx (2048 blks) | wtrans (512 blks) | catb (1) --
__global__ __launch_bounds__(256) void prep_k(
    const float* __restrict__ X, unsigned short* __restrict__ Xb,
    const float* __restrict__ Wq, const float* __restrict__ Wk,
    const float* __restrict__ Wv, const float* __restrict__ Wo,
    const float* __restrict__ W1, const float* __restrict__ W2,
    unsigned short* __restrict__ WqkvT, unsigned short* __restrict__ WoT,
    unsigned short* __restrict__ W1T, unsigned short* __restrict__ W2T,
    const float* __restrict__ bq, const float* __restrict__ bk,
    const float* __restrict__ bv, float* __restrict__ Bqkv) {
  __shared__ float t[64][65];
  int bid = blockIdx.x, tid = threadIdx.x;
  if (bid < 2048) {  // cast x -> bf16
    int i = bid * 256 + tid;
    const float* p = X + (size_t)i * 8;
    float4 a = *(const float4*)(p);
    float4 b = *(const float4*)(p + 4);
    short8 o;
    o[0] = (short)f2b(a.x); o[1] = (short)f2b(a.y);
    o[2] = (short)f2b(a.z); o[3] = (short)f2b(a.w);
    o[4] = (short)f2b(b.x); o[5] = (short)f2b(b.y);
    o[6] = (short)f2b(b.z); o[7] = (short)f2b(b.w);
    *(short8*)(Xb + (size_t)i * 8) = o;
    return;
  }
  if (bid == 2560) {  // concat biases (bq pre-scaled)
    for (int i = tid; i < 1536; i += 256) {
      float v = (i < 512) ? bq[i] * QSCALE : (i < 1024 ? bk[i - 512] : bv[i - 1024]);
      Bqkv[i] = v;
    }
    return;
  }
  // weight transpose sections
  int idx = bid - 2048;
  const float* W; unsigned short* WT; int K, N, kb, nb; float scale = 1.0f;
  if (idx < 256) {
    int sec = idx >> 6, local = idx & 63;
    K = 512; N = 512; kb = local >> 3; nb = local & 7;
    if (sec == 0) { W = Wq; WT = WqkvT; scale = QSCALE; }
    else if (sec == 1) { W = Wk; WT = WqkvT + 512 * 512; }
    else if (sec == 2) { W = Wv; WT = WqkvT + 2 * 512 * 512; }
    else { W = Wo; WT = WoT; }
  } else if (idx < 384) {
    int local = idx - 256; K = 512; N = 1024; kb = local >> 4; nb = local & 15;
    W = W1; WT = W1T;
  } else {
    int local = idx - 384; K = 1024; N = 512; kb = local >> 3; nb = local & 7;
    W = W2; WT = W2T;
  }
  int k0 = kb * 64, n0 = nb * 64;
  for (int i = tid; i < 4096; i += 256) {
    int r = i >> 6, c = i & 63;
    t[r][c] = W[(size_t)(k0 + r) * N + n0 + c];
  }
  __syncthreads();
  for (int i = tid; i < 4096; i += 256) {
    int r = i >> 6, c = i & 63;
    WT[(size_t)(n0 + r) * K + k0 + c] = f2b(t[c][r] * scale);
  }
}

// ---------------- GEMM 128x128, depth-2 pipelined (3 buffers, vmcnt(8)) ----
// EPI: 2 = bf16 out + relu,
//      3 = QKV: col<1024 -> Q/K bf16 (col>>9 segment); col>=1024 -> V written
//          TRANSPOSED into Vt[(b*8+h)*64+d][s] (Vt passed via Cf slot).
// XCD-aware bijective work swizzle (T1).
template <int EPI>
__global__ __launch_bounds__(256) void gemm_bt(
    const unsigned short* __restrict__ A, const unsigned short* __restrict__ BT,
    const float* __restrict__ bias, float* __restrict__ Cf,
    unsigned short* __restrict__ Cb, int M, int N, int K) {
  __shared__ unsigned short As[3][128 * 32];
  __shared__ unsigned short Bs[3][128 * 32];
  int t = threadIdx.x, w = t >> 6, l = t & 63;
  int linb = blockIdx.x + gridDim.x * blockIdx.y;
  int q8 = (gridDim.x * gridDim.y) >> 3;  // nwg % 8 == 0 for all our grids
  int wk = (linb & 7) * q8 + (linb >> 3);
  int bm = wk / gridDim.y, bn = wk % gridDim.y;
  int wm = w >> 1, wn = w & 1;
  int g = l >> 4, ln = l & 15;
  f32x4 acc[4][4] = {};
  const unsigned short* Arow = A + (size_t)bm * 128 * K;
  const unsigned short* Brow = BT + (size_t)bn * 128 * K;
  int nk = K >> 5;

  auto stageg = [&](int buf, int kt) {
    int k0 = kt * 32;
#pragma unroll
    for (int i = 0; i < 2; ++i) {
      int cl = i * 256 + t;
      int r = cl >> 2, c = cl & 3;
      char* ldsA = (char*)&As[buf][0] + (size_t)(i * 256 + w * 64) * 16;
      char* ldsB = (char*)&Bs[buf][0] + (size_t)(i * 256 + w * 64) * 16;
      gl16(Arow + (size_t)r * K + k0 + c * 8, ldsA);
      gl16(Brow + (size_t)r * K + k0 + c * 8, ldsB);
    }
  };

  stageg(0, 0);
  stageg(1, 1);
  int cur = 0, sbuf = 2;
  for (int kt = 0; kt < nk; ++kt) {
    if (kt + 2 < nk) {
      stageg(sbuf, kt + 2);
      asm volatile("s_waitcnt vmcnt(8)" ::: "memory");  // drain cur's 4 loads
    } else if (kt + 1 < nk) {
      asm volatile("s_waitcnt vmcnt(4)" ::: "memory");
    } else {
      asm volatile("s_waitcnt vmcnt(0)" ::: "memory");
    }
    __builtin_amdgcn_s_barrier();
    __builtin_amdgcn_sched_barrier(0);
    short8 af[4], bf[4];
    int ko = g * 8;
#pragma unroll
    for (int i = 0; i < 4; ++i)
      af[i] = *(const short8*)&As[cur][(wm * 64 + i * 16 + ln) * 32 + ko];
#pragma unroll
    for (int j = 0; j < 4; ++j)
      bf[j] = *(const short8*)&Bs[cur][(wn * 64 + j * 16 + ln) * 32 + ko];
    __builtin_amdgcn_s_setprio(1);
#pragma unroll
    for (int i = 0; i < 4; ++i)
#pragma unroll
      for (int j = 0; j < 4; ++j)
        acc[i][j] = __builtin_amdgcn_mfma_f32_16x16x32_bf16(af[i], bf[j], acc[i][j], 0, 0, 0);
    __builtin_amdgcn_s_setprio(0);
    __builtin_amdgcn_s_barrier();  // all waves done reading cur before restage
    int old = cur;
    cur = (cur == 2) ? 0 : cur + 1;
    sbuf = old;
  }
#pragma unroll
  for (int i = 0; i < 4; ++i) {
    int row = bm * 128 + wm * 64 + i * 16 + g * 4;
#pragma unroll
    for (int j = 0; j < 4; ++j) {
      int col = bn * 128 + wn * 64 + j * 16 + ln;
      float bv = bias[col];
      float vv[4];
#pragma unroll
      for (int r = 0; r < 4; ++r) {
        float v = acc[i][j][r] + bv;
        if constexpr (EPI == 2) v = v > 0.f ? v : 0.f;
        vv[r] = v;
      }
      if constexpr (EPI == 3) {
        if (col < 1024) {
#pragma unroll
          for (int r = 0; r < 4; ++r)
            Cb[(size_t)(col >> 9) * 4194304 + (size_t)(row + r) * 512 + (col & 511)] = f2b(vv[r]);
        } else {
          short4v pk;
#pragma unroll
          for (int r = 0; r < 4; ++r) pk[r] = (short)f2b(vv[r]);
          *(short4v*)((unsigned short*)Cf +
                      (size_t)((row >> 12) * 512 + (col & 511)) * 4096 + (row & 4095)) = pk;
        }
      } else {
#pragma unroll
        for (int r = 0; r < 4; ++r)
          Cb[(size_t)(row + r) * N + col] = f2b(vv[r]);
      }
    }
  }
}

// ------- fused GEMM(N=512) + bias + residual + LayerNorm, 4 waves ----------
// 256 threads = 4 waves; block = 32 rows x FULL 512 cols (wave: 128 cols).
// grid = 256 -> 2 blocks/CU (cross-block overlap hides K-step stalls).
// AMODE 0: A = global bf16, double-buffered with B (counted vmcnt).
// AMODE 1: A = combine of 2 Opart planes, prestaged ONCE into XOR-swizzled
//          32KB LDS; B single-buffered (32KB) so two blocks co-reside.
// B-staging: 8 iters x 256 threads x 16B = full 32KB panel per K-step.
template <int AMODE, bool WB>
__global__ __launch_bounds__(256) void gemmln_k(
    const unsigned short* __restrict__ A, const unsigned short* __restrict__ BT,
    const float* __restrict__ bias, const float* __restrict__ X,
    const float* __restrict__ gamma, const float* __restrict__ beta,
    float* __restrict__ outf, unsigned short* __restrict__ outb,
    const unsigned short* __restrict__ Opart, const float* __restrict__ L,
    int K) {
  __shared__ unsigned short As[AMODE ? 32 * 512 : 2 * 32 * 32];
  __shared__ unsigned short Bs[AMODE ? 512 * 32 : 2 * 512 * 32];
  __shared__ float stats[4][32][2];
  __shared__ float minv[32][2];
  __shared__ float sli[8][32];
  int tid = threadIdx.x, wv = tid >> 6, lane = tid & 63;
  int g = lane >> 4, ln = lane & 15;
  int bm = blockIdx.x;
  int row0 = bm * 32;
  f32x4 acc[2][8] = {};

  if constexpr (AMODE == 1) {
    // ---- prestage combined attention-output A-tile [32 q][512 hd] ----
    int b = row0 >> 12;
    int q0 = row0 & 4095;
    {
      int h = tid >> 5, qq = tid & 31;
      int bh = b * 8 + h;
      float s = L[(size_t)bh * 4096 + q0 + qq] + L[(size_t)(16 + bh) * 4096 + q0 + qq];
      sli[h][qq] = 1.0f / s;
    }
    __syncthreads();
#pragma unroll
    for (int cc = 0; cc < 2; ++cc) {
      int col = cc * 256 + tid;
      int h = col >> 6, d = col & 63;
      int bh = b * 8 + h;
      const unsigned short* p0 = Opart + (size_t)bh * 262144 + (size_t)d * 4096 + q0;
      const unsigned short* p1 = Opart + (size_t)(16 + bh) * 262144 + (size_t)d * 4096 + q0;
#pragma unroll
      for (int i = 0; i < 4; ++i) {
        short8 a = *(const short8*)(p0 + i * 8);
        short8 c = *(const short8*)(p1 + i * 8);
#pragma unroll
        for (int j = 0; j < 8; ++j) {
          int qq = i * 8 + j;
          float s = (b2f((unsigned short)a[j]) + b2f((unsigned short)c[j])) * sli[h][qq];
          As[qq * 512 + (col ^ ((qq & 7) << 3))] = f2b(s);  // XOR-swizzled
        }
      }
    }
    __syncthreads();
  }

  const unsigned short* Arow = (AMODE == 0) ? (A + (size_t)bm * 32 * K) : nullptr;
  int nk = K >> 5;

  auto stageg = [&](int buf, int kt) {
    int k0 = kt * 32;
    if constexpr (AMODE == 0) {
      if (tid < 128) {
        int r = tid >> 2, c = tid & 3;
        gl16(Arow + (size_t)r * K + k0 + c * 8, (char*)As + (size_t)buf * 2048 + tid * 16);
      }
    }
#pragma unroll
    for (int i = 0; i < 8; ++i) {
      int u = i * 256 + tid;
      int r = u >> 2, c = u & 3;
      gl16(BT + (size_t)r * K + k0 + c * 8,
           (char*)Bs + (AMODE ? 0 : (size_t)buf * 32768) + (size_t)u * 16);
    }
  };

  if constexpr (AMODE == 0) stageg(0, 0);
  for (int kt = 0; kt < nk; ++kt) {
    int cur = kt & 1;
    if constexpr (AMODE == 1) {
      stageg(0, kt);
      asm volatile("s_waitcnt vmcnt(0)" ::: "memory");
    } else {
      if (kt + 1 < nk) {
        stageg(cur ^ 1, kt + 1);
        if (wv < 2) asm volatile("s_waitcnt vmcnt(9)" ::: "memory");
        else        asm volatile("s_waitcnt vmcnt(8)" ::: "memory");
      } else {
        asm volatile("s_waitcnt vmcnt(0)" ::: "memory");
      }
    }
    __builtin_amdgcn_s_barrier();
    __builtin_amdgcn_sched_barrier(0);
    int k0 = kt * 32;
    short8 af[2], bf[8];
#pragma unroll
    for (int i = 0; i < 2; ++i) {
      int row = i * 16 + ln;
      if constexpr (AMODE == 1) {
        int c16 = (k0 >> 3) + g;
        af[i] = *(const short8*)&As[row * 512 + ((c16 ^ (row & 7)) << 3)];
      } else {
        af[i] = *(const short8*)&As[cur * 1024 + row * 32 + g * 8];
      }
    }
#pragma unroll
    for (int j = 0; j < 8; ++j)
      bf[j] = *(const short8*)&Bs[(AMODE ? 0 : cur * 16384) +
                                  (wv * 128 + j * 16 + ln) * 32 + g * 8];
    __builtin_amdgcn_s_setprio(1);
#pragma unroll
    for (int i = 0; i < 2; ++i)
#pragma unroll
      for (int j = 0; j < 8; ++j)
        acc[i][j] = __builtin_amdgcn_mfma_f32_16x16x32_bf16(af[i], bf[j], acc[i][j], 0, 0, 0);
    __builtin_amdgcn_s_setprio(0);
    __builtin_amdgcn_s_barrier();
  }
  float v[2][8][4];
  float ps[8], pss[8];
#pragma unroll
  for (int k = 0; k < 8; ++k) { ps[k] = 0.f; pss[k] = 0.f; }
#pragma unroll
  for (int i = 0; i < 2; ++i)
#pragma unroll
    for (int j = 0; j < 8; ++j) {
      int col = wv * 128 + j * 16 + ln;
      float bv = bias[col];
#pragma unroll
      for (int r = 0; r < 4; ++r) {
        int row = i * 16 + g * 4 + r;
        float t = acc[i][j][r] + bv + X[(size_t)(row0 + row) * 512 + col];
        v[i][j][r] = t;
        ps[i * 4 + r] += t; pss[i * 4 + r] += t * t;
      }
    }
#pragma unroll
  for (int off = 1; off < 16; off <<= 1) {
#pragma unroll
    for (int k = 0; k < 8; ++k) {
      ps[k] += __shfl_xor(ps[k], off);
      pss[k] += __shfl_xor(pss[k], off);
    }
  }
  if (ln == 0) {
#pragma unroll
    for (int i = 0; i < 2; ++i)
#pragma unroll
      for (int r = 0; r < 4; ++r) {
        stats[wv][i * 16 + g * 4 + r][0] = ps[i * 4 + r];
        stats[wv][i * 16 + g * 4 + r][1] = pss[i * 4 + r];
      }
  }
  __syncthreads();
  if (tid < 32) {
    float S = 0.f, SS = 0.f;
#pragma unroll
    for (int w2 = 0; w2 < 4; ++w2) { S += stats[w2][tid][0]; SS += stats[w2][tid][1]; }
    float mean = S * (1.f / 512.f);
    float var = fmaxf((SS - 512.f * mean * mean) * (1.f / 511.f), 0.f);
    minv[tid][0] = mean;
    minv[tid][1] = 1.f / (sqrtf(var) + 1e-6f);
  }
  __syncthreads();
#pragma unroll
  for (int i = 0; i < 2; ++i)
#pragma unroll
    for (int j = 0; j < 8; ++j) {
      int col = wv * 128 + j * 16 + ln;
      float gm = gamma[col], bt2 = beta[col];
#pragma unroll
      for (int r = 0; r < 4; ++r) {
        int row = i * 16 + g * 4 + r;
        float o = gm * ((v[i][j][r] - minv[row][0]) * minv[row][1]) + bt2;
        outf[(size_t)(row0 + row) * 512 + col] = o;
        if constexpr (WB) outb[(size_t)(row0 + row) * 512 + col] = f2b(o);
      }
    }
}

// ---------------- flash attention, log2-softmax, KV-split-2, 64q/wave ------
// Q pre-scaled by 0.125*log2e at the weight level -> p = exp2(s) directly.
// XCD-aware work swizzle keeps each XCD's K/V L2-resident (FETCH 70->16MB).
__global__ __launch_bounds__(256, 2) void attn_k(
    const unsigned short* __restrict__ Q, const unsigned short* __restrict__ Kb,
    const unsigned short* __restrict__ Vt, unsigned short* __restrict__ Opart,
    float* __restrict__ L) {
  __shared__ unsigned short Ks[2][4096];
  __shared__ unsigned short Vs[3][4096];
  int tid = threadIdx.x, wv = tid >> 6, lane = tid & 63;
  int l31 = lane & 31, hi = lane >> 5;
  int lin = blockIdx.x + 16 * blockIdx.y + 256 * blockIdx.z;  // grid (16,16,2)
  int wk = (lin & 7) * 64 + (lin >> 3);                        // bijective, 512 wgs
  int qb = wk & 15, bh = (wk >> 4) & 15, z = wk >> 8;
  int b = bh >> 3, h = bh & 7;
  int q0 = qb * 256 + wv * 64;
  int kvbase = z * 2048;

  short8 qfA[4], qfB[4];
  {
    const unsigned short* qpA = Q + (size_t)(b * 4096 + q0 + l31) * 512 + h * 64;
    const unsigned short* qpB = qpA + 32 * 512;
#pragma unroll
    for (int ks = 0; ks < 4; ++ks) {
      qfA[ks] = *(const short8*)(qpA + ks * 16 + hi * 8);
      qfB[ks] = *(const short8*)(qpB + ks * 16 + hi * 8);
    }
  }

  short8 ones;
#pragma unroll
  for (int j = 0; j < 8; ++j) ones[j] = (short)0x3F80;

  const f32x16 Z = {};
  f32x16 oA0 = {}, oA1 = {}, oB0 = {}, oB1 = {}, laccA = {}, laccB = {};

  int skk[2], sc[2];
#pragma unroll
  for (int i = 0; i < 2; ++i) {
    int u = i * 256 + tid;
    int r2 = u >> 4, s = u & 15;
    skk[i] = 2 * r2 + (s & 1);
    sc[i] = ((s >> 1) ^ (r2 & 7)) * 8;
  }

  auto stage = [&](char* kb_lds, char* vb_lds, int kv) {
    const unsigned short* ksrc = Kb + (size_t)(b * 4096 + kv) * 512 + h * 64;
    const unsigned short* vsrc = Vt + (size_t)(bh * 64) * 4096 + kv;
#pragma unroll
    for (int i = 0; i < 2; ++i) {
      gl16(ksrc + (size_t)skk[i] * 512 + sc[i], kb_lds + (size_t)(i * 256 + wv * 64) * 16);
      gl16(vsrc + (size_t)skk[i] * 4096 + sc[i], vb_lds + (size_t)(i * 256 + wv * 64) * 16);
    }
  };

  int r2a = l31 >> 1, par = l31 & 1, perm = r2a & 7;
  int rdb = r2a * 256 + (par << 4);

  auto qk = [&](const char* kbase, f32x16& sA0, f32x16& sA1, f32x16& sB0, f32x16& sB1) {
    __builtin_amdgcn_s_setprio(1);
#pragma unroll
    for (int ks = 0; ks < 4; ++ks) {
      int c16 = ks * 2 + hi;
      int byteA = rdb + (((c16 ^ perm) << 1) << 4);
      short8 k0 = *(const short8*)(kbase + byteA);
      short8 k1 = *(const short8*)(kbase + byteA + 4096);
      if (ks == 0) {
        sA0 = __builtin_amdgcn_mfma_f32_32x32x16_bf16(k0, qfA[0], Z, 0, 0, 0);
        sA1 = __builtin_amdgcn_mfma_f32_32x32x16_bf16(k1, qfA[0], Z, 0, 0, 0);
        sB0 = __builtin_amdgcn_mfma_f32_32x32x16_bf16(k0, qfB[0], Z, 0, 0, 0);
        sB1 = __builtin_amdgcn_mfma_f32_32x32x16_bf16(k1, qfB[0], Z, 0, 0, 0);
      } else {
        sA0 = __builtin_amdgcn_mfma_f32_32x32x16_bf16(k0, qfA[ks], sA0, 0, 0, 0);
        sA1 = __builtin_amdgcn_mfma_f32_32x32x16_bf16(k1, qfA[ks], sA1, 0, 0, 0);
        sB0 = __builtin_amdgcn_mfma_f32_32x32x16_bf16(k0, qfB[ks], sB0, 0, 0, 0);
        sB1 = __builtin_amdgcn_mfma_f32_32x32x16_bf16(k1, qfB[ks], sB1, 0, 0, 0);
      }
    }
    __builtin_amdgcn_s_setprio(0);
  };

  auto pv = [&](const char* vbase, const short8* pfA, const short8* pfB) {
    __builtin_amdgcn_s_setprio(1);
#pragma unroll
    for (int ks = 0; ks < 4; ++ks) {
      int c16 = ks * 2 + hi;
      int byteA = rdb + (((c16 ^ perm) << 1) << 4);
      short8 v0 = *(const short8*)(vbase + byteA);
      short8 v1 = *(const short8*)(vbase + byteA + 4096);
      oA0 = __builtin_amdgcn_mfma_f32_32x32x16_bf16(v0, pfA[ks], oA0, 0, 0, 0);
      oA1 = __builtin_amdgcn_mfma_f32_32x32x16_bf16(v1, pfA[ks], oA1, 0, 0, 0);
      oB0 = __builtin_amdgcn_mfma_f32_32x32x16_bf16(v0, pfB[ks], oB0, 0, 0, 0);
      oB1 = __builtin_amdgcn_mfma_f32_32x32x16_bf16(v1, pfB[ks], oB1, 0, 0, 0);
      laccA = __builtin_amdgcn_mfma_f32_32x32x16_bf16(ones, pfA[ks], laccA, 0, 0, 0);
      laccB = __builtin_amdgcn_mfma_f32_32x32x16_bf16(ones, pfB[ks], laccB, 0, 0, 0);
    }
    __builtin_amdgcn_s_setprio(0);
  };

  auto exppack = [&](f32x16& s0, f32x16& s1, short8* pf) {
#pragma unroll
    for (int r = 0; r < 16; ++r) s0[r] = __builtin_amdgcn_exp2f(s0[r]);
#pragma unroll
    for (int r = 0; r < 16; ++r) s1[r] = __builtin_amdgcn_exp2f(s1[r]);
    unsigned int u0 = cvtpk(s0[0], s0[1]), u1 = cvtpk(s0[4], s0[5]);
    plswap(u0, u1);
    unsigned int u2 = cvtpk(s0[2], s0[3]), u3 = cvtpk(s0[6], s0[7]);
    plswap(u2, u3);
    unsigned int u4 = cvtpk(s0[8], s0[9]), u5 = cvtpk(s0[12], s0[13]);
    plswap(u4, u5);
    unsigned int u6 = cvtpk(s0[10], s0[11]), u7 = cvtpk(s0[14], s0[15]);
    plswap(u6, u7);
    union { u32x4 u; short8 s; } cv;
    cv.u = (u32x4){u0, u2, u1, u3}; pf[0] = cv.s;
    cv.u = (u32x4){u4, u6, u5, u7}; pf[1] = cv.s;
    unsigned int w0 = cvtpk(s1[0], s1[1]), w1 = cvtpk(s1[4], s1[5]);
    plswap(w0, w1);
    unsigned int w2 = cvtpk(s1[2], s1[3]), w3 = cvtpk(s1[6], s1[7]);
    plswap(w2, w3);
    unsigned int w4 = cvtpk(s1[8], s1[9]), w5 = cvtpk(s1[12], s1[13]);
    plswap(w4, w5);
    unsigned int w6 = cvtpk(s1[10], s1[11]), w7 = cvtpk(s1[14], s1[15]);
    plswap(w6, w7);
    cv.u = (u32x4){w0, w2, w1, w3}; pf[2] = cv.s;
    cv.u = (u32x4){w4, w6, w5, w7}; pf[3] = cv.s;
  };

  char* k0b = (char*)&Ks[0][0];
  char* k1b = (char*)&Ks[1][0];
  char* vA = (char*)&Vs[0][0];
  char* vB = (char*)&Vs[1][0];
  char* vC = (char*)&Vs[2][0];
  stage(k0b, vA, kvbase);
  __syncthreads();
  stage(k1b, vB, kvbase + 64);

  f32x16 sA0, sA1, sB0, sB1;
  qk(k0b, sA0, sA1, sB0, sB1);
  short8 pfA[4], pfB[4];
  exppack(sA0, sA1, pfA);
  exppack(sB0, sB1, pfB);

#pragma unroll 1
  for (int t = 1; t < 32; ++t) {
    __syncthreads();
    char* kr = (t & 1) ? k1b : k0b;
    char* kw = (t & 1) ? k0b : k1b;
    if (t < 31) stage(kw, vC, kvbase + (t + 1) * 64);
    qk(kr, sA0, sA1, sB0, sB1);
    pv(vA, pfA, pfB);
    exppack(sA0, sA1, pfA);
    exppack(sB0, sB1, pfB);
    char* tmp = vA; vA = vB; vB = vC; vC = tmp;
  }
  pv(vA, pfA, pfB);

  int plane = z * 16 + bh;
  unsigned short* op = Opart + (size_t)plane * 262144;
  int qA = q0 + l31, qB = q0 + 32 + l31;
#pragma unroll
  for (int r = 0; r < 16; ++r) {
    int dr = (r & 3) + 8 * (r >> 2) + 4 * hi;
    op[(size_t)dr * 4096 + qA] = f2b(oA0[r]);
    op[(size_t)(dr + 32) * 4096 + qA] = f2b(oA1[r]);
    op[(size_t)dr * 4096 + qB] = f2b(oB0[r]);
    op[(size_t)(dr + 32) * 4096 + qB] = f2b(oB1[r]);
  }
  if (hi == 0) {
    L[(size_t)plane * 4096 + qA] = laccA[0];
    L[(size_t)plane * 4096 + qB] = laccB[0];
  }
}

extern "C" void kernel_launch(void* const* d_in, const int* in_sizes, int n_in,
                              void* d_out, int out_size, void* d_ws, size_t ws_size,
                              hipStream_t stream) {
  const float* x  = (const float*)d_in[0];
  const float* Wq = (const float*)d_in[1];
  const float* bq = (const float*)d_in[2];
  const float* Wk = (const float*)d_in[3];
  const float* bk = (const float*)d_in[4];
  const float* Wv = (const float*)d_in[5];
  const float* bv = (const float*)d_in[6];
  const float* Wo = (const float*)d_in[7];
  const float* bo = (const float*)d_in[8];
  const float* a1 = (const float*)d_in[9];
  const float* b1 = (const float*)d_in[10];
  const float* a2 = (const float*)d_in[11];
  const float* b2 = (const float*)d_in[12];
  const float* W1 = (const float*)d_in[13];
  const float* c1 = (const float*)d_in[14];
  const float* W2 = (const float*)d_in[15];
  const float* c2 = (const float*)d_in[16];

  char* ws = (char*)d_ws;
  const size_t MB = 1024 * 1024;
  unsigned short* Xb  = (unsigned short*)(ws + 0);        // 8MB
  unsigned short* Qb  = (unsigned short*)(ws + 8 * MB);   // 8MB; later Y1b
  unsigned short* Kbf = (unsigned short*)(ws + 16 * MB);  // 8MB; later H lo
  float* L = (float*)(ws + 24 * MB);                      // 512KB (attn); later H hi
  unsigned short* Vtb = (unsigned short*)(ws + 32 * MB);  // 8MB
  unsigned short* WqkvT = (unsigned short*)(ws + 40 * MB);
  unsigned short* WoT = (unsigned short*)(ws + 41 * MB + 512 * 1024);
  unsigned short* W1T = (unsigned short*)(ws + 42 * MB);
  unsigned short* W2T = (unsigned short*)(ws + 43 * MB);
  unsigned short* Opart = (unsigned short*)(ws + 44 * MB);  // 16MB (attn phase)
  float* Bqkv = (float*)(ws + 44 * MB);  // 6KB, QKV-gemm phase only (pre-attn)
  float* Y1 = (float*)(ws + 60 * MB);    // 16MB f32
  unsigned short* Y1b = Qb;
  unsigned short* Hb  = Kbf;  // 16MB spanning Kbf + L region

  prep_k<<<2561, 256, 0, stream>>>(x, Xb, Wq, Wk, Wv, Wo, W1, W2,
                                   WqkvT, WoT, W1T, W2T, bq, bk, bv, Bqkv);

  // fused QKV: Q,K -> Qb/Kbf; V -> Vtb (transposed in-epilogue)
  gemm_bt<3><<<dim3(64, 12), 256, 0, stream>>>(Xb, WqkvT, Bqkv, (float*)Vtb, Qb, 8192, 1536, 512);

  attn_k<<<dim3(16, 16, 2), 256, 0, stream>>>(Qb, Kbf, Vtb, Opart, L);

  // Wo GEMM (A = combined attention output, fused comb) + residual(x) + LN1
  gemmln_k<1, true><<<256, 256, 0, stream>>>(nullptr, WoT, bo, x, a1, b1, Y1, Y1b,
                                             Opart, L, 512);
  // FFN1 + relu -> Hb
  gemm_bt<2><<<dim3(64, 8), 256, 0, stream>>>(Y1b, W1T, c1, nullptr, Hb, 8192, 1024, 512);
  // FFN2 GEMM + residual(Y1) + LN2 -> d_out
  gemmln_k<0, false><<<256, 256, 0, stream>>>(Hb, W2T, c2, Y1, a2, b2, (float*)d_out, nullptr,
                                              nullptr, nullptr, 1024);
}

// Round 17
// 188.200 us; speedup vs baseline: 1.0287x; 1.0287x over previous
//
#include <hip/hip_runtime.h>
#include <stdint.h>

typedef short short8 __attribute__((ext_vector_type(8)));
typedef short short4v __attribute__((ext_vector_type(4)));
typedef float f32x4 __attribute__((ext_vector_type(4)));
typedef float f32x16 __attribute__((ext_vector_type(16)));
typedef unsigned int u32x4 __attribute__((ext_vector_type(4)));

#define LOG2E 1.44269504088896f
#define QSCALE (0.125f * LOG2E)

__device__ __forceinline__ unsigned short f2b(float f) {
  union { float f; unsigned int u; } x; x.f = f;
  unsigned int u = x.u;
  unsigned int r = (u + 0x7fffu + ((u >> 16) & 1u)) >> 16;
  return (unsigned short)r;
}
__device__ __forceinline__ float b2f(unsigned short s) {
  union { unsigned int u; float f; } x; x.u = ((unsigned int)s) << 16;
  return x.f;
}
__device__ __forceinline__ void gl16(const void* g, void* l) {
  __builtin_amdgcn_global_load_lds((const __attribute__((address_space(1))) void*)g,
                                   (__attribute__((address_space(3))) void*)l, 16, 0, 0);
}
__device__ __forceinline__ unsigned int cvtpk(float lo, float hi) {
  unsigned int r;
  asm("v_cvt_pk_bf16_f32 %0, %1, %2" : "=v"(r) : "v"(lo), "v"(hi));
  return r;
}
__device__ __forceinline__ void plswap(unsigned int& a, unsigned int& b) {
  asm volatile("v_permlane32_swap_b32 %0, %1" : "+v"(a), "+v"(b));
}

// ------- merged prologue: castx (2048 blks) | wtrans (512 blks) | catb (1) --
__global__ __launch_bounds__(256) void prep_k(
    const float* __restrict__ X, unsigned short* __restrict__ Xb,
    const float* __restrict__ Wq, const float* __restrict__ Wk,
    const float* __restrict__ Wv, const float* __restrict__ Wo,
    const float* __restrict__ W1, const float* __restrict__ W2,
    unsigned short* __restrict__ WqkvT, unsigned short* __restrict__ WoT,
    unsigned short* __restrict__ W1T, unsigned short* __restrict__ W2T,
    const float* __restrict__ bq, const float* __restrict__ bk,
    const float* __restrict__ bv, float* __restrict__ Bqkv) {
  __shared__ float t[64][65];
  int bid = blockIdx.x, tid = threadIdx.x;
  if (bid < 2048) {  // cast x -> bf16
    int i = bid * 256 + tid;
    const float* p = X + (size_t)i * 8;
    float4 a = *(const float4*)(p);
    float4 b = *(const float4*)(p + 4);
    short8 o;
    o[0] = (short)f2b(a.x); o[1] = (short)f2b(a.y);
    o[2] = (short)f2b(a.z); o[3] = (short)f2b(a.w);
    o[4] = (short)f2b(b.x); o[5] = (short)f2b(b.y);
    o[6] = (short)f2b(b.z); o[7] = (short)f2b(b.w);
    *(short8*)(Xb + (size_t)i * 8) = o;
    return;
  }
  if (bid == 2560) {  // concat biases (bq pre-scaled)
    for (int i = tid; i < 1536; i += 256) {
      float v = (i < 512) ? bq[i] * QSCALE : (i < 1024 ? bk[i - 512] : bv[i - 1024]);
      Bqkv[i] = v;
    }
    return;
  }
  // weight transpose sections
  int idx = bid - 2048;
  const float* W; unsigned short* WT; int K, N, kb, nb; float scale = 1.0f;
  if (idx < 256) {
    int sec = idx >> 6, local = idx & 63;
    K = 512; N = 512; kb = local >> 3; nb = local & 7;
    if (sec == 0) { W = Wq; WT = WqkvT; scale = QSCALE; }
    else if (sec == 1) { W = Wk; WT = WqkvT + 512 * 512; }
    else if (sec == 2) { W = Wv; WT = WqkvT + 2 * 512 * 512; }
    else { W = Wo; WT = WoT; }
  } else if (idx < 384) {
    int local = idx - 256; K = 512; N = 1024; kb = local >> 4; nb = local & 15;
    W = W1; WT = W1T;
  } else {
    int local = idx - 384; K = 1024; N = 512; kb = local >> 3; nb = local & 7;
    W = W2; WT = W2T;
  }
  int k0 = kb * 64, n0 = nb * 64;
  for (int i = tid; i < 4096; i += 256) {
    int r = i >> 6, c = i & 63;
    t[r][c] = W[(size_t)(k0 + r) * N + n0 + c];
  }
  __syncthreads();
  for (int i = tid; i < 4096; i += 256) {
    int r = i >> 6, c = i & 63;
    WT[(size_t)(n0 + r) * K + k0 + c] = f2b(t[c][r] * scale);
  }
}

// ---------------- GEMM 128x128, double-buffered (T4 counted vmcnt) ----
// EPI: 2 = bf16 out + relu,
//      3 = QKV: col<1024 -> Q/K bf16 (col>>9 segment); col>=1024 -> V written
//          TRANSPOSED into Vt[(b*8+h)*64+d][s] (Vt passed via Cf slot).
// XCD-aware bijective work swizzle (T1).
template <int EPI>
__global__ __launch_bounds__(256) void gemm_bt(
    const unsigned short* __restrict__ A, const unsigned short* __restrict__ BT,
    const float* __restrict__ bias, float* __restrict__ Cf,
    unsigned short* __restrict__ Cb, int M, int N, int K) {
  __shared__ unsigned short As[2][128 * 32];
  __shared__ unsigned short Bs[2][128 * 32];
  int t = threadIdx.x, w = t >> 6, l = t & 63;
  int linb = blockIdx.x + gridDim.x * blockIdx.y;
  int q8 = (gridDim.x * gridDim.y) >> 3;  // nwg % 8 == 0 for all our grids
  int wk = (linb & 7) * q8 + (linb >> 3);
  int bm = wk / gridDim.y, bn = wk % gridDim.y;
  int wm = w >> 1, wn = w & 1;
  int g = l >> 4, ln = l & 15;
  f32x4 acc[4][4] = {};
  const unsigned short* Arow = A + (size_t)bm * 128 * K;
  const unsigned short* Brow = BT + (size_t)bn * 128 * K;
  int nk = K >> 5;

  auto stageg = [&](int buf, int kt) {
    int k0 = kt * 32;
#pragma unroll
    for (int i = 0; i < 2; ++i) {
      int cl = i * 256 + t;
      int r = cl >> 2, c = cl & 3;
      char* ldsA = (char*)&As[buf][0] + (size_t)(i * 256 + w * 64) * 16;
      char* ldsB = (char*)&Bs[buf][0] + (size_t)(i * 256 + w * 64) * 16;
      gl16(Arow + (size_t)r * K + k0 + c * 8, ldsA);
      gl16(Brow + (size_t)r * K + k0 + c * 8, ldsB);
    }
  };

  stageg(0, 0);
  for (int kt = 0; kt < nk; ++kt) {
    int cur = kt & 1;
    if (kt + 1 < nk) {
      stageg(cur ^ 1, kt + 1);
      asm volatile("s_waitcnt vmcnt(4)" ::: "memory");  // wait cur's 4 loads only
    } else {
      asm volatile("s_waitcnt vmcnt(0)" ::: "memory");
    }
    __builtin_amdgcn_s_barrier();
    __builtin_amdgcn_sched_barrier(0);
    short8 af[4], bf[4];
    int ko = g * 8;
#pragma unroll
    for (int i = 0; i < 4; ++i)
      af[i] = *(const short8*)&As[cur][(wm * 64 + i * 16 + ln) * 32 + ko];
#pragma unroll
    for (int j = 0; j < 4; ++j)
      bf[j] = *(const short8*)&Bs[cur][(wn * 64 + j * 16 + ln) * 32 + ko];
    __builtin_amdgcn_s_setprio(1);
#pragma unroll
    for (int i = 0; i < 4; ++i)
#pragma unroll
      for (int j = 0; j < 4; ++j)
        acc[i][j] = __builtin_amdgcn_mfma_f32_16x16x32_bf16(af[i], bf[j], acc[i][j], 0, 0, 0);
    __builtin_amdgcn_s_setprio(0);
    __builtin_amdgcn_s_barrier();  // all waves done reading cur before overwrite
  }
#pragma unroll
  for (int i = 0; i < 4; ++i) {
    int row = bm * 128 + wm * 64 + i * 16 + g * 4;
#pragma unroll
    for (int j = 0; j < 4; ++j) {
      int col = bn * 128 + wn * 64 + j * 16 + ln;
      float bv = bias[col];
      float vv[4];
#pragma unroll
      for (int r = 0; r < 4; ++r) {
        float v = acc[i][j][r] + bv;
        if constexpr (EPI == 2) v = v > 0.f ? v : 0.f;
        vv[r] = v;
      }
      if constexpr (EPI == 3) {
        if (col < 1024) {
#pragma unroll
          for (int r = 0; r < 4; ++r)
            Cb[(size_t)(col >> 9) * 4194304 + (size_t)(row + r) * 512 + (col & 511)] = f2b(vv[r]);
        } else {
          short4v pk;
#pragma unroll
          for (int r = 0; r < 4; ++r) pk[r] = (short)f2b(vv[r]);
          *(short4v*)((unsigned short*)Cf +
                      (size_t)((row >> 12) * 512 + (col & 511)) * 4096 + (row & 4095)) = pk;
        }
      } else {
#pragma unroll
        for (int r = 0; r < 4; ++r)
          Cb[(size_t)(row + r) * N + col] = f2b(vv[r]);
      }
    }
  }
}

// ------- fused GEMM(N=512) + bias + residual + LayerNorm, B double-buffered -
// 512 threads = 8 waves; block = 32 rows x FULL 512 cols. grid = 256.
// AMODE 0: A = global bf16, staged per K-step (double-buffered with B).
// AMODE 1: A = combine of 2 Opart planes, prestaged ONCE into padded LDS.
template <int AMODE, bool WB>
__global__ __launch_bounds__(512) void gemmln_k(
    const unsigned short* __restrict__ A, const unsigned short* __restrict__ BT,
    const float* __restrict__ bias, const float* __restrict__ X,
    const float* __restrict__ gamma, const float* __restrict__ beta,
    float* __restrict__ outf, unsigned short* __restrict__ outb,
    const unsigned short* __restrict__ Opart, const float* __restrict__ L,
    int K) {
  __shared__ unsigned short As[AMODE ? 32 * 520 : 2 * 32 * 32];
  __shared__ unsigned short Bs[2][512 * 32];
  __shared__ float stats[8][32][2];
  __shared__ float minv[32][2];
  __shared__ float sli[8][32];
  int tid = threadIdx.x, wv = tid >> 6, lane = tid & 63;
  int g = lane >> 4, ln = lane & 15;
  int bm = blockIdx.x;
  int row0 = bm * 32;
  f32x4 acc[2][4] = {};

  if constexpr (AMODE == 1) {
    // ---- prestage combined attention-output A-tile [32 q][512 hd] ----
    int b = row0 >> 12;
    int q0 = row0 & 4095;
    if (tid < 256) {
      int h = tid >> 5, qq = tid & 31;
      int bh = b * 8 + h;
      float s = L[(size_t)bh * 4096 + q0 + qq] + L[(size_t)(16 + bh) * 4096 + q0 + qq];
      sli[h][qq] = 1.0f / s;
    }
    __syncthreads();
    int col = tid;  // 512 cols, one per thread
    int h = col >> 6, d = col & 63;
    int bh = b * 8 + h;
    const unsigned short* p0 = Opart + (size_t)bh * 262144 + (size_t)d * 4096 + q0;
    const unsigned short* p1 = Opart + (size_t)(16 + bh) * 262144 + (size_t)d * 4096 + q0;
#pragma unroll
    for (int i = 0; i < 4; ++i) {
      short8 a = *(const short8*)(p0 + i * 8);
      short8 c = *(const short8*)(p1 + i * 8);
#pragma unroll
      for (int j = 0; j < 8; ++j) {
        int qq = i * 8 + j;
        float s = (b2f((unsigned short)a[j]) + b2f((unsigned short)c[j])) * sli[h][qq];
        As[qq * 520 + col] = f2b(s);
      }
    }
    __syncthreads();
  }

  const unsigned short* Arow = (AMODE == 0) ? (A + (size_t)bm * 32 * K) : nullptr;
  int nk = K >> 5;

  auto stageg = [&](int buf, int kt) {
    int k0 = kt * 32;
    if constexpr (AMODE == 0) {
      if (tid < 128) {
        int r = tid >> 2, c = tid & 3;
        gl16(Arow + (size_t)r * K + k0 + c * 8, (char*)As + (size_t)buf * 2048 + tid * 16);
      }
    }
#pragma unroll
    for (int i = 0; i < 4; ++i) {
      int u = i * 512 + tid;
      int r = u >> 2, c = u & 3;
      gl16(BT + (size_t)r * K + k0 + c * 8, (char*)&Bs[buf][0] + (size_t)u * 16);
    }
  };

  stageg(0, 0);
  for (int kt = 0; kt < nk; ++kt) {
    int cur = kt & 1;
    if (kt + 1 < nk) {
      stageg(cur ^ 1, kt + 1);
      if constexpr (AMODE == 0) {
        if (wv < 2) asm volatile("s_waitcnt vmcnt(5)" ::: "memory");
        else        asm volatile("s_waitcnt vmcnt(4)" ::: "memory");
      } else {
        asm volatile("s_waitcnt vmcnt(4)" ::: "memory");
      }
    } else {
      asm volatile("s_waitcnt vmcnt(0)" ::: "memory");
    }
    __builtin_amdgcn_s_barrier();
    __builtin_amdgcn_sched_barrier(0);
    int k0 = kt * 32;
    short8 af[2], bf[4];
#pragma unroll
    for (int i = 0; i < 2; ++i) {
      if constexpr (AMODE == 1)
        af[i] = *(const short8*)&As[(i * 16 + ln) * 520 + k0 + g * 8];
      else
        af[i] = *(const short8*)&As[cur * 1024 + (i * 16 + ln) * 32 + g * 8];
    }
#pragma unroll
    for (int j = 0; j < 4; ++j)
      bf[j] = *(const short8*)&Bs[cur][(wv * 64 + j * 16 + ln) * 32 + g * 8];
    __builtin_amdgcn_s_setprio(1);
#pragma unroll
    for (int i = 0; i < 2; ++i)
#pragma unroll
      for (int j = 0; j < 4; ++j)
        acc[i][j] = __builtin_amdgcn_mfma_f32_16x16x32_bf16(af[i], bf[j], acc[i][j], 0, 0, 0);
    __builtin_amdgcn_s_setprio(0);
    __builtin_amdgcn_s_barrier();
  }
  float v[2][4][4];
  float ps[8], pss[8];
#pragma unroll
  for (int k = 0; k < 8; ++k) { ps[k] = 0.f; pss[k] = 0.f; }
#pragma unroll
  for (int i = 0; i < 2; ++i)
#pragma unroll
    for (int j = 0; j < 4; ++j) {
      int col = wv * 64 + j * 16 + ln;
      float bv = bias[col];
#pragma unroll
      for (int r = 0; r < 4; ++r) {
        int row = i * 16 + g * 4 + r;
        float t = acc[i][j][r] + bv + X[(size_t)(row0 + row) * 512 + col];
        v[i][j][r] = t;
        ps[i * 4 + r] += t; pss[i * 4 + r] += t * t;
      }
    }
#pragma unroll
  for (int off = 1; off < 16; off <<= 1) {
#pragma unroll
    for (int k = 0; k < 8; ++k) {
      ps[k] += __shfl_xor(ps[k], off);
      pss[k] += __shfl_xor(pss[k], off);
    }
  }
  if (ln == 0) {
#pragma unroll
    for (int i = 0; i < 2; ++i)
#pragma unroll
      for (int r = 0; r < 4; ++r) {
        stats[wv][i * 16 + g * 4 + r][0] = ps[i * 4 + r];
        stats[wv][i * 16 + g * 4 + r][1] = pss[i * 4 + r];
      }
  }
  __syncthreads();
  if (tid < 32) {
    float S = 0.f, SS = 0.f;
#pragma unroll
    for (int w2 = 0; w2 < 8; ++w2) { S += stats[w2][tid][0]; SS += stats[w2][tid][1]; }
    float mean = S * (1.f / 512.f);
    float var = fmaxf((SS - 512.f * mean * mean) * (1.f / 511.f), 0.f);
    minv[tid][0] = mean;
    minv[tid][1] = 1.f / (sqrtf(var) + 1e-6f);
  }
  __syncthreads();
#pragma unroll
  for (int i = 0; i < 2; ++i)
#pragma unroll
    for (int j = 0; j < 4; ++j) {
      int col = wv * 64 + j * 16 + ln;
      float gm = gamma[col], bt2 = beta[col];
#pragma unroll
      for (int r = 0; r < 4; ++r) {
        int row = i * 16 + g * 4 + r;
        float o = gm * ((v[i][j][r] - minv[row][0]) * minv[row][1]) + bt2;
        outf[(size_t)(row0 + row) * 512 + col] = o;
        if constexpr (WB) outb[(size_t)(row0 + row) * 512 + col] = f2b(o);
      }
    }
}

// ---------------- flash attention, log2-softmax, KV-split-2, 64q/wave ------
// Q pre-scaled by 0.125*log2e at the weight level -> p = exp2(s) directly.
// XCD-aware work swizzle keeps each XCD's K/V L2-resident (FETCH 70->16MB).
__global__ __launch_bounds__(256, 2) void attn_k(
    const unsigned short* __restrict__ Q, const unsigned short* __restrict__ Kb,
    const unsigned short* __restrict__ Vt, unsigned short* __restrict__ Opart,
    float* __restrict__ L) {
  __shared__ unsigned short Ks[2][4096];
  __shared__ unsigned short Vs[3][4096];
  int tid = threadIdx.x, wv = tid >> 6, lane = tid & 63;
  int l31 = lane & 31, hi = lane >> 5;
  int lin = blockIdx.x + 16 * blockIdx.y + 256 * blockIdx.z;  // grid (16,16,2)
  int wk = (lin & 7) * 64 + (lin >> 3);                        // bijective, 512 wgs
  int qb = wk & 15, bh = (wk >> 4) & 15, z = wk >> 8;
  int b = bh >> 3, h = bh & 7;
  int q0 = qb * 256 + wv * 64;
  int kvbase = z * 2048;

  short8 qfA[4], qfB[4];
  {
    const unsigned short* qpA = Q + (size_t)(b * 4096 + q0 + l31) * 512 + h * 64;
    const unsigned short* qpB = qpA + 32 * 512;
#pragma unroll
    for (int ks = 0; ks < 4; ++ks) {
      qfA[ks] = *(const short8*)(qpA + ks * 16 + hi * 8);
      qfB[ks] = *(const short8*)(qpB + ks * 16 + hi * 8);
    }
  }

  short8 ones;
#pragma unroll
  for (int j = 0; j < 8; ++j) ones[j] = (short)0x3F80;

  const f32x16 Z = {};
  f32x16 oA0 = {}, oA1 = {}, oB0 = {}, oB1 = {}, laccA = {}, laccB = {};

  int skk[2], sc[2];
#pragma unroll
  for (int i = 0; i < 2; ++i) {
    int u = i * 256 + tid;
    int r2 = u >> 4, s = u & 15;
    skk[i] = 2 * r2 + (s & 1);
    sc[i] = ((s >> 1) ^ (r2 & 7)) * 8;
  }

  auto stage = [&](char* kb_lds, char* vb_lds, int kv) {
    const unsigned short* ksrc = Kb + (size_t)(b * 4096 + kv) * 512 + h * 64;
    const unsigned short* vsrc = Vt + (size_t)(bh * 64) * 4096 + kv;
#pragma unroll
    for (int i = 0; i < 2; ++i) {
      gl16(ksrc + (size_t)skk[i] * 512 + sc[i], kb_lds + (size_t)(i * 256 + wv * 64) * 16);
      gl16(vsrc + (size_t)skk[i] * 4096 + sc[i], vb_lds + (size_t)(i * 256 + wv * 64) * 16);
    }
  };

  int r2a = l31 >> 1, par = l31 & 1, perm = r2a & 7;
  int rdb = r2a * 256 + (par << 4);

  auto qk = [&](const char* kbase, f32x16& sA0, f32x16& sA1, f32x16& sB0, f32x16& sB1) {
    __builtin_amdgcn_s_setprio(1);
#pragma unroll
    for (int ks = 0; ks < 4; ++ks) {
      int c16 = ks * 2 + hi;
      int byteA = rdb + (((c16 ^ perm) << 1) << 4);
      short8 k0 = *(const short8*)(kbase + byteA);
      short8 k1 = *(const short8*)(kbase + byteA + 4096);
      if (ks == 0) {
        sA0 = __builtin_amdgcn_mfma_f32_32x32x16_bf16(k0, qfA[0], Z, 0, 0, 0);
        sA1 = __builtin_amdgcn_mfma_f32_32x32x16_bf16(k1, qfA[0], Z, 0, 0, 0);
        sB0 = __builtin_amdgcn_mfma_f32_32x32x16_bf16(k0, qfB[0], Z, 0, 0, 0);
        sB1 = __builtin_amdgcn_mfma_f32_32x32x16_bf16(k1, qfB[0], Z, 0, 0, 0);
      } else {
        sA0 = __builtin_amdgcn_mfma_f32_32x32x16_bf16(k0, qfA[ks], sA0, 0, 0, 0);
        sA1 = __builtin_amdgcn_mfma_f32_32x32x16_bf16(k1, qfA[ks], sA1, 0, 0, 0);
        sB0 = __builtin_amdgcn_mfma_f32_32x32x16_bf16(k0, qfB[ks], sB0, 0, 0, 0);
        sB1 = __builtin_amdgcn_mfma_f32_32x32x16_bf16(k1, qfB[ks], sB1, 0, 0, 0);
      }
    }
    __builtin_amdgcn_s_setprio(0);
  };

  auto pv = [&](const char* vbase, const short8* pfA, const short8* pfB) {
    __builtin_amdgcn_s_setprio(1);
#pragma unroll
    for (int ks = 0; ks < 4; ++ks) {
      int c16 = ks * 2 + hi;
      int byteA = rdb + (((c16 ^ perm) << 1) << 4);
      short8 v0 = *(const short8*)(vbase + byteA);
      short8 v1 = *(const short8*)(vbase + byteA + 4096);
      oA0 = __builtin_amdgcn_mfma_f32_32x32x16_bf16(v0, pfA[ks], oA0, 0, 0, 0);
      oA1 = __builtin_amdgcn_mfma_f32_32x32x16_bf16(v1, pfA[ks], oA1, 0, 0, 0);
      oB0 = __builtin_amdgcn_mfma_f32_32x32x16_bf16(v0, pfB[ks], oB0, 0, 0, 0);
      oB1 = __builtin_amdgcn_mfma_f32_32x32x16_bf16(v1, pfB[ks], oB1, 0, 0, 0);
      laccA = __builtin_amdgcn_mfma_f32_32x32x16_bf16(ones, pfA[ks], laccA, 0, 0, 0);
      laccB = __builtin_amdgcn_mfma_f32_32x32x16_bf16(ones, pfB[ks], laccB, 0, 0, 0);
    }
    __builtin_amdgcn_s_setprio(0);
  };

  auto exppack = [&](f32x16& s0, f32x16& s1, short8* pf) {
#pragma unroll
    for (int r = 0; r < 16; ++r) s0[r] = __builtin_amdgcn_exp2f(s0[r]);
#pragma unroll
    for (int r = 0; r < 16; ++r) s1[r] = __builtin_amdgcn_exp2f(s1[r]);
    unsigned int u0 = cvtpk(s0[0], s0[1]), u1 = cvtpk(s0[4], s0[5]);
    plswap(u0, u1);
    unsigned int u2 = cvtpk(s0[2], s0[3]), u3 = cvtpk(s0[6], s0[7]);
    plswap(u2, u3);
    unsigned int u4 = cvtpk(s0[8], s0[9]), u5 = cvtpk(s0[12], s0[13]);
    plswap(u4, u5);
    unsigned int u6 = cvtpk(s0[10], s0[11]), u7 = cvtpk(s0[14], s0[15]);
    plswap(u6, u7);
    union { u32x4 u; short8 s; } cv;
    cv.u = (u32x4){u0, u2, u1, u3}; pf[0] = cv.s;
    cv.u = (u32x4){u4, u6, u5, u7}; pf[1] = cv.s;
    unsigned int w0 = cvtpk(s1[0], s1[1]), w1 = cvtpk(s1[4], s1[5]);
    plswap(w0, w1);
    unsigned int w2 = cvtpk(s1[2], s1[3]), w3 = cvtpk(s1[6], s1[7]);
    plswap(w2, w3);
    unsigned int w4 = cvtpk(s1[8], s1[9]), w5 = cvtpk(s1[12], s1[13]);
    plswap(w4, w5);
    unsigned int w6 = cvtpk(s1[10], s1[11]), w7 = cvtpk(s1[14], s1[15]);
    plswap(w6, w7);
    cv.u = (u32x4){w0, w2, w1, w3}; pf[2] = cv.s;
    cv.u = (u32x4){w4, w6, w5, w7}; pf[3] = cv.s;
  };

  char* k0b = (char*)&Ks[0][0];
  char* k1b = (char*)&Ks[1][0];
  char* vA = (char*)&Vs[0][0];
  char* vB = (char*)&Vs[1][0];
  char* vC = (char*)&Vs[2][0];
  stage(k0b, vA, kvbase);
  __syncthreads();
  stage(k1b, vB, kvbase + 64);

  f32x16 sA0, sA1, sB0, sB1;
  qk(k0b, sA0, sA1, sB0, sB1);
  short8 pfA[4], pfB[4];
  exppack(sA0, sA1, pfA);
  exppack(sB0, sB1, pfB);

#pragma unroll 1
  for (int t = 1; t < 32; ++t) {
    __syncthreads();
    char* kr = (t & 1) ? k1b : k0b;
    char* kw = (t & 1) ? k0b : k1b;
    if (t < 31) stage(kw, vC, kvbase + (t + 1) * 64);
    qk(kr, sA0, sA1, sB0, sB1);
    pv(vA, pfA, pfB);
    exppack(sA0, sA1, pfA);
    exppack(sB0, sB1, pfB);
    char* tmp = vA; vA = vB; vB = vC; vC = tmp;
  }
  pv(vA, pfA, pfB);

  int plane = z * 16 + bh;
  unsigned short* op = Opart + (size_t)plane * 262144;
  int qA = q0 + l31, qB = q0 + 32 + l31;
#pragma unroll
  for (int r = 0; r < 16; ++r) {
    int dr = (r & 3) + 8 * (r >> 2) + 4 * hi;
    op[(size_t)dr * 4096 + qA] = f2b(oA0[r]);
    op[(size_t)(dr + 32) * 4096 + qA] = f2b(oA1[r]);
    op[(size_t)dr * 4096 + qB] = f2b(oB0[r]);
    op[(size_t)(dr + 32) * 4096 + qB] = f2b(oB1[r]);
  }
  if (hi == 0) {
    L[(size_t)plane * 4096 + qA] = laccA[0];
    L[(size_t)plane * 4096 + qB] = laccB[0];
  }
}

extern "C" void kernel_launch(void* const* d_in, const int* in_sizes, int n_in,
                              void* d_out, int out_size, void* d_ws, size_t ws_size,
                              hipStream_t stream) {
  const float* x  = (const float*)d_in[0];
  const float* Wq = (const float*)d_in[1];
  const float* bq = (const float*)d_in[2];
  const float* Wk = (const float*)d_in[3];
  const float* bk = (const float*)d_in[4];
  const float* Wv = (const float*)d_in[5];
  const float* bv = (const float*)d_in[6];
  const float* Wo = (const float*)d_in[7];
  const float* bo = (const float*)d_in[8];
  const float* a1 = (const float*)d_in[9];
  const float* b1 = (const float*)d_in[10];
  const float* a2 = (const float*)d_in[11];
  const float* b2 = (const float*)d_in[12];
  const float* W1 = (const float*)d_in[13];
  const float* c1 = (const float*)d_in[14];
  const float* W2 = (const float*)d_in[15];
  const float* c2 = (const float*)d_in[16];

  char* ws = (char*)d_ws;
  const size_t MB = 1024 * 1024;
  unsigned short* Xb  = (unsigned short*)(ws + 0);        // 8MB
  unsigned short* Qb  = (unsigned short*)(ws + 8 * MB);   // 8MB; later Y1b
  unsigned short* Kbf = (unsigned short*)(ws + 16 * MB);  // 8MB; later H lo
  float* L = (float*)(ws + 24 * MB);                      // 512KB (attn); later H hi
  unsigned short* Vtb = (unsigned short*)(ws + 32 * MB);  // 8MB
  unsigned short* WqkvT = (unsigned short*)(ws + 40 * MB);
  unsigned short* WoT = (unsigned short*)(ws + 41 * MB + 512 * 1024);
  unsigned short* W1T = (unsigned short*)(ws + 42 * MB);
  unsigned short* W2T = (unsigned short*)(ws + 43 * MB);
  unsigned short* Opart = (unsigned short*)(ws + 44 * MB);  // 16MB (attn phase)
  float* Bqkv = (float*)(ws + 44 * MB);  // 6KB, QKV-gemm phase only (pre-attn)
  float* Y1 = (float*)(ws + 60 * MB);    // 16MB f32
  unsigned short* Y1b = Qb;
  unsigned short* Hb  = Kbf;  // 16MB spanning Kbf + L region

  prep_k<<<2561, 256, 0, stream>>>(x, Xb, Wq, Wk, Wv, Wo, W1, W2,
                                   WqkvT, WoT, W1T, W2T, bq, bk, bv, Bqkv);

  // fused QKV: Q,K -> Qb/Kbf; V -> Vtb (transposed in-epilogue)
  gemm_bt<3><<<dim3(64, 12), 256, 0, stream>>>(Xb, WqkvT, Bqkv, (float*)Vtb, Qb, 8192, 1536, 512);

  attn_k<<<dim3(16, 16, 2), 256, 0, stream>>>(Qb, Kbf, Vtb, Opart, L);

  // Wo GEMM (A = combined attention output, fused comb) + residual(x) + LN1
  gemmln_k<1, true><<<256, 512, 0, stream>>>(nullptr, WoT, bo, x, a1, b1, Y1, Y1b,
                                             Opart, L, 512);
  // FFN1 + relu -> Hb
  gemm_bt<2><<<dim3(64, 8), 256, 0, stream>>>(Y1b, W1T, c1, nullptr, Hb, 8192, 1024, 512);
  // FFN2 GEMM + residual(Y1) + LN2 -> d_out
  gemmln_k<0, false><<<256, 512, 0, stream>>>(Hb, W2T, c2, Y1, a2, b2, (float*)d_out, nullptr,
                                              nullptr, nullptr, 1024);
}